// Round 1
// baseline (2102.666 us; speedup 1.0000x reference)
//
#include <hip/hip_runtime.h>
#include <math.h>

#define NN 100000
#define NE 1600000
#define DD 64
#define HID 512
#define NCLS 393

// ---------------- degree / dinv ----------------
__global__ void k_deg_init(float* __restrict__ deg) {
    int i = blockIdx.x * 256 + threadIdx.x;
    if (i < NN) deg[i] = 1.0f;  // self-loop
}

__global__ void k_deg_count(const int* __restrict__ dst, float* __restrict__ deg) {
    int e = blockIdx.x * 256 + threadIdx.x;
    if (e < NE) atomicAdd(&deg[dst[e]], 1.0f);
}

__global__ void k_dinv(float* __restrict__ deg) {
    int i = blockIdx.x * 256 + threadIdx.x;
    if (i < NN) deg[i] = rsqrtf(deg[i]);  // deg >= 1 guaranteed
}

// ---------------- row GEMM: t = act(x) @ W (+bout) ----------------
// 4 rows per 256-thread block. W (64x64) staged in LDS.
// IN_ACT: x := relu(x + bin) on load (fuses previous layer's bias+ReLU)
// SELF_INIT: also write outAcc[n][j] = t*dinv[n]^2 (self-loop term of scatter-sum)
// OUT_BIAS: t += bout
template<bool IN_ACT, bool SELF_INIT, bool OUT_BIAS>
__global__ void k_gemm64(const float* __restrict__ x, const float* __restrict__ W,
                         const float* __restrict__ bin, const float* __restrict__ bout,
                         const float* __restrict__ dinv,
                         float* __restrict__ outT, float* __restrict__ outAcc) {
    __shared__ float Ws[64 * 64];
    __shared__ float xs[4][64];
    int tid = threadIdx.x;
    for (int i = tid; i < 64 * 64; i += 256) Ws[i] = W[i];
    int r = tid >> 6, j = tid & 63;
    int n = blockIdx.x * 4 + r;
    float xv = 0.f;
    if (n < NN) {
        xv = x[n * 64 + j];
        if (IN_ACT) xv = fmaxf(xv + bin[j], 0.f);
    }
    xs[r][j] = xv;
    __syncthreads();
    if (n < NN) {
        float acc = 0.f;
#pragma unroll
        for (int k = 0; k < 64; ++k) acc = fmaf(xs[r][k], Ws[k * 64 + j], acc);
        if (OUT_BIAS) acc += bout[j];
        outT[n * 64 + j] = acc;
        if (SELF_INIT) {
            float dv = dinv[n];
            outAcc[n * 64 + j] = acc * dv * dv;
        }
    }
}

// ---------------- edge scatter: acc[dst] += t[src] * dinv[src]*dinv[dst] ----------------
__global__ void k_scatter(const int* __restrict__ src, const int* __restrict__ dst,
                          const float* __restrict__ t, const float* __restrict__ dinv,
                          float* __restrict__ acc) {
    int lane = threadIdx.x & 63;
    int e = (blockIdx.x * 256 + threadIdx.x) >> 6;
    if (e >= NE) return;
    int s = src[e], d = dst[e];
    float norm = dinv[s] * dinv[d];
    atomicAdd(&acc[(size_t)d * 64 + lane], t[(size_t)s * 64 + lane] * norm);
}

// ---------------- zero small buffer ----------------
__global__ void k_zero(float* __restrict__ p, int n) {
    int i = blockIdx.x * 256 + threadIdx.x;
    if (i < n) p[i] = 0.f;
}

// ---------------- transpose GEMM: P[64,512] = scores^T @ W4 ----------------
// grid = 8 colTiles * 49 kChunks; each block: 64-col tile, 2048-node K chunk.
#define KCHUNK 2048
#define KSUB 128
__global__ void k_tgemm(const float* __restrict__ scores, const float* __restrict__ W4,
                        float* __restrict__ P) {
    __shared__ float ss[KSUB][64];
    int colTile = blockIdx.x & 7;
    int kChunk = blockIdx.x >> 3;
    int tid = threadIdx.x;
    int tc = tid & 63, tr = tid >> 6;  // tr uniform per wave -> LDS broadcast
    int col = colTile * 64 + tc;
    float acc[16];
#pragma unroll
    for (int i = 0; i < 16; ++i) acc[i] = 0.f;
    int k0 = kChunk * KCHUNK;
    int k1 = min(k0 + KCHUNK, NN);
    for (int kb = k0; kb < k1; kb += KSUB) {
        int cnt = min(KSUB, k1 - kb);
        __syncthreads();
        for (int i = tid; i < cnt * 64; i += 256)
            ss[i >> 6][i & 63] = scores[(size_t)(kb + (i >> 6)) * 64 + (i & 63)];
        __syncthreads();
        for (int nIt = 0; nIt < cnt; ++nIt) {
            float w = W4[(size_t)(kb + nIt) * 512 + col];
#pragma unroll
            for (int i = 0; i < 16; ++i) acc[i] = fmaf(ss[nIt][4 * i + tr], w, acc[i]);
        }
    }
#pragma unroll
    for (int i = 0; i < 16; ++i) atomicAdd(&P[(4 * i + tr) * 512 + col], acc[i]);
}

// ---------------- final: logits = relu(P+b4) @ W5 + b5; log_softmax rows ----------------
__global__ void k_final(const float* __restrict__ P, const float* __restrict__ b4,
                        const float* __restrict__ W5, const float* __restrict__ b5,
                        float* __restrict__ out) {
    __shared__ float p[HID];
    __shared__ float z[NCLS];
    __shared__ float red[256];
    int i = blockIdx.x;  // output row 0..63
    int tid = threadIdx.x;
    for (int k = tid; k < HID; k += 256) p[k] = fmaxf(P[i * HID + k] + b4[k], 0.f);
    __syncthreads();
    for (int c = tid; c < NCLS; c += 256) {
        float acc = b5[c];
        for (int k = 0; k < HID; ++k) acc = fmaf(p[k], W5[(size_t)k * NCLS + c], acc);
        z[c] = acc;
    }
    __syncthreads();
    float m = -INFINITY;
    for (int c = tid; c < NCLS; c += 256) m = fmaxf(m, z[c]);
    red[tid] = m;
    __syncthreads();
    for (int s = 128; s > 0; s >>= 1) {
        if (tid < s) red[tid] = fmaxf(red[tid], red[tid + s]);
        __syncthreads();
    }
    m = red[0];
    __syncthreads();
    float sum = 0.f;
    for (int c = tid; c < NCLS; c += 256) sum += expf(z[c] - m);
    red[tid] = sum;
    __syncthreads();
    for (int s = 128; s > 0; s >>= 1) {
        if (tid < s) red[tid] += red[tid + s];
        __syncthreads();
    }
    float lse = m + logf(red[0]);
    for (int c = tid; c < NCLS; c += 256) out[i * NCLS + c] = z[c] - lse;
}

extern "C" void kernel_launch(void* const* d_in, const int* in_sizes, int n_in,
                              void* d_out, int out_size, void* d_ws, size_t ws_size,
                              hipStream_t stream) {
    const int* adj = (const int*)d_in[0];
    const int* src = adj;
    const int* dst = adj + NE;
    const float* feat = (const float*)d_in[1];
    const float* W1 = (const float*)d_in[2];
    const float* b1 = (const float*)d_in[3];
    const float* W2 = (const float*)d_in[4];
    const float* b2 = (const float*)d_in[5];
    const float* W3 = (const float*)d_in[6];
    const float* b3 = (const float*)d_in[7];
    const float* Wlin = (const float*)d_in[8];
    const float* blin = (const float*)d_in[9];
    const float* W4 = (const float*)d_in[10];
    const float* b4 = (const float*)d_in[11];
    const float* W5 = (const float*)d_in[12];
    const float* b5 = (const float*)d_in[13];
    float* out = (float*)d_out;

    float* ws = (float*)d_ws;
    float* dinv = ws;                       // NN
    float* bufA = dinv + NN;                // NN*64
    float* bufB = bufA + (size_t)NN * 64;   // NN*64
    float* P = bufB + (size_t)NN * 64;      // 64*512

    const int NB_N = (NN + 255) / 256;
    const int NB_E = (NE + 255) / 256;
    const int NB_G = NN / 4;           // 25000 (NN % 4 == 0)
    const int NB_S = NE / 4;           // 400000 (4 edges/block, wave per edge)
    const int NB_T = 8 * ((NN + KCHUNK - 1) / KCHUNK);  // 8 * 49

    // degree normalization (shared by all 3 conv layers)
    k_deg_init<<<NB_N, 256, 0, stream>>>(dinv);
    k_deg_count<<<NB_E, 256, 0, stream>>>(dst, dinv);
    k_dinv<<<NB_N, 256, 0, stream>>>(dinv);

    // layer 1: t = feat @ W1 ; acc = t*dinv^2 ; scatter edges
    k_gemm64<false, true, false><<<NB_G, 256, 0, stream>>>(feat, W1, nullptr, nullptr, dinv, bufA, bufB);
    k_scatter<<<NB_S, 256, 0, stream>>>(src, dst, bufA, dinv, bufB);
    // layer 2: x = relu(bufB + b1)
    k_gemm64<true, true, false><<<NB_G, 256, 0, stream>>>(bufB, W2, b1, nullptr, dinv, bufA, bufB);
    k_scatter<<<NB_S, 256, 0, stream>>>(src, dst, bufA, dinv, bufB);
    // layer 3
    k_gemm64<true, true, false><<<NB_G, 256, 0, stream>>>(bufB, W3, b2, nullptr, dinv, bufA, bufB);
    k_scatter<<<NB_S, 256, 0, stream>>>(src, dst, bufA, dinv, bufB);
    // scores = relu(bufB + b3) @ Wlin + blin -> bufA
    k_gemm64<true, false, true><<<NB_G, 256, 0, stream>>>(bufB, Wlin, b3, blin, dinv, bufA, nullptr);

    // P = scores^T @ W4 (atomic K-split)
    k_zero<<<(64 * HID + 255) / 256, 256, 0, stream>>>(P, 64 * HID);
    k_tgemm<<<NB_T, 256, 0, stream>>>(bufA, W4, P);

    // logits + log_softmax
    k_final<<<64, 256, 0, stream>>>(P, b4, W5, b5, out);
}

// Round 2
// 1073.670 us; speedup vs baseline: 1.9584x; 1.9584x over previous
//
#include <hip/hip_runtime.h>
#include <math.h>

#define NN 100000
#define NE 1600000
#define HID 512
#define NCLS 393

// ---------------- CSR build ----------------
__global__ void k_init(int* __restrict__ cnt, int* __restrict__ gtot) {
    int i = blockIdx.x * 256 + threadIdx.x;
    if (i < NN) cnt[i] = 0;
    if (i == 0) *gtot = 0;
}

__global__ void k_count(const int* __restrict__ dst, int* __restrict__ cnt) {
    int e = blockIdx.x * 256 + threadIdx.x;
    if (e < NE) atomicAdd(&cnt[dst[e]], 1);
}

// dinv = rsqrt(1+cnt); off = bump-alloc (any disjoint contiguous ranges are valid CSR); cur = 0
__global__ void k_off(const int* __restrict__ cnt, float* __restrict__ dinv,
                      int* __restrict__ off, int* __restrict__ cur, int* __restrict__ gtot) {
    int i = blockIdx.x * 256 + threadIdx.x;
    if (i < NN) {
        int c = cnt[i];
        dinv[i] = rsqrtf(1.0f + (float)c);
        off[i] = atomicAdd(gtot, c);
        cur[i] = 0;
    }
}

__global__ void k_fill(const int* __restrict__ src, const int* __restrict__ dst,
                       const float* __restrict__ dinv, const int* __restrict__ off,
                       int* __restrict__ cur, int* __restrict__ eidx, float* __restrict__ enorm) {
    int e = blockIdx.x * 256 + threadIdx.x;
    if (e < NE) {
        int s = src[e], d = dst[e];
        int pos = off[d] + atomicAdd(&cur[d], 1);
        eidx[pos] = s;
        enorm[pos] = dinv[s] * dinv[d];
    }
}

// ---------------- row GEMM: out = act(x) @ W (+bout) ----------------
// 32 rows/block, 256 threads. W column held in 64 VGPRs; x rows read as b128 LDS broadcasts.
template<bool IN_ACT, bool OUT_BIAS>
__global__ void k_gemm64b(const float* __restrict__ x, const float* __restrict__ W,
                          const float* __restrict__ bin, const float* __restrict__ bout,
                          float* __restrict__ out) {
    __shared__ float Ws[64 * 64];
    __shared__ float xs[32 * 64];
    int tid = threadIdx.x;
    size_t n0 = (size_t)blockIdx.x * 32;
    for (int i = tid; i < 1024; i += 256)
        ((float4*)Ws)[i] = ((const float4*)W)[i];
    for (int i = tid; i < 512; i += 256) {
        float4 v = ((const float4*)(x + n0 * 64))[i];
        if (IN_ACT) {
            int c = (i & 15) * 4;
            float4 bv = *(const float4*)(bin + c);
            v.x = fmaxf(v.x + bv.x, 0.f);
            v.y = fmaxf(v.y + bv.y, 0.f);
            v.z = fmaxf(v.z + bv.z, 0.f);
            v.w = fmaxf(v.w + bv.w, 0.f);
        }
        ((float4*)xs)[i] = v;
    }
    __syncthreads();
    int j = tid & 63, q = tid >> 6;
    float Wreg[64];
#pragma unroll
    for (int k = 0; k < 64; ++k) Wreg[k] = Ws[k * 64 + j];
    float bo = OUT_BIAS ? bout[j] : 0.f;
    for (int r = 0; r < 8; ++r) {
        int row = q * 8 + r;
        float acc = bo;
        const float4* xr = (const float4*)(xs + row * 64);
#pragma unroll
        for (int k4 = 0; k4 < 16; ++k4) {
            float4 xv = xr[k4];
            acc = fmaf(xv.x, Wreg[k4 * 4 + 0], acc);
            acc = fmaf(xv.y, Wreg[k4 * 4 + 1], acc);
            acc = fmaf(xv.z, Wreg[k4 * 4 + 2], acc);
            acc = fmaf(xv.w, Wreg[k4 * 4 + 3], acc);
        }
        out[(n0 + row) * 64 + j] = acc;
    }
}

// ---------------- CSR gather: out[n] = t[n]*dinv[n]^2 + sum_e t[src_e]*norm_e ----------------
// one wave per node, lane = feature; edge metadata loaded 64-at-a-time, broadcast via shfl.
__global__ void k_gather(const int* __restrict__ eidx, const float* __restrict__ enorm,
                         const int* __restrict__ off, const int* __restrict__ cnt,
                         const float* __restrict__ dinv, const float* __restrict__ t,
                         float* __restrict__ out) {
    int lane = threadIdx.x & 63;
    int n = (blockIdx.x * 256 + threadIdx.x) >> 6;
    if (n >= NN) return;
    float dv = dinv[n];
    float acc = t[(size_t)n * 64 + lane] * dv * dv;
    int o = off[n], c = cnt[n];
    for (int b = 0; b < c; b += 64) {
        int m = min(64, c - b);
        int sIdx = 0;
        float nrm = 0.f;
        if (lane < m) {
            sIdx = eidx[o + b + lane];
            nrm = enorm[o + b + lane];
        }
        int e = 0;
        for (; e + 4 <= m; e += 4) {
            int s0 = __shfl(sIdx, e + 0); float w0 = __shfl(nrm, e + 0);
            int s1 = __shfl(sIdx, e + 1); float w1 = __shfl(nrm, e + 1);
            int s2 = __shfl(sIdx, e + 2); float w2 = __shfl(nrm, e + 2);
            int s3 = __shfl(sIdx, e + 3); float w3 = __shfl(nrm, e + 3);
            float v0 = t[(size_t)s0 * 64 + lane];
            float v1 = t[(size_t)s1 * 64 + lane];
            float v2 = t[(size_t)s2 * 64 + lane];
            float v3 = t[(size_t)s3 * 64 + lane];
            acc = fmaf(v0, w0, acc);
            acc = fmaf(v1, w1, acc);
            acc = fmaf(v2, w2, acc);
            acc = fmaf(v3, w3, acc);
        }
        for (; e < m; ++e) {
            int s0 = __shfl(sIdx, e); float w0 = __shfl(nrm, e);
            acc = fmaf(t[(size_t)s0 * 64 + lane], w0, acc);
        }
    }
    out[(size_t)n * 64 + lane] = acc;
}

// ---------------- zero ----------------
__global__ void k_zero(float* __restrict__ p, int n) {
    int i = blockIdx.x * 256 + threadIdx.x;
    if (i < n) p[i] = 0.f;
}

// ---------------- transpose GEMM: P[64,512] += scores^T @ W4 ----------------
// block: 64 rows x 128 cols, K-chunk of 384 nodes. float4 W4 loads; scores via LDS b128 broadcast.
#define TG_KCHUNK 384
#define TG_NCH ((NN + TG_KCHUNK - 1) / TG_KCHUNK)
__global__ void k_tgemm2(const float* __restrict__ scores, const float* __restrict__ W4,
                         float* __restrict__ P) {
    __shared__ float ss[64 * 64];
    int colT = blockIdx.x & 3;
    int kch = blockIdx.x >> 2;
    int tid = threadIdx.x;
    int tc = tid & 31, tr = tid >> 5;  // tr in [0,8): rows tr*8..tr*8+7
    int col = colT * 128 + tc * 4;
    float acc[8][4];
#pragma unroll
    for (int i = 0; i < 8; ++i)
#pragma unroll
        for (int c = 0; c < 4; ++c) acc[i][c] = 0.f;
    int k0 = kch * TG_KCHUNK;
    int k1 = min(k0 + TG_KCHUNK, NN);
    for (int kb = k0; kb < k1; kb += 64) {
        int cnt = min(64, k1 - kb);
        __syncthreads();
        for (int i = tid; i < 1024; i += 256) {
            float4 v = {0.f, 0.f, 0.f, 0.f};
            if ((i >> 4) < cnt) v = ((const float4*)(scores + (size_t)kb * 64))[i];
            ((float4*)ss)[i] = v;
        }
        __syncthreads();
        const float4* w4p = (const float4*)(W4 + (size_t)kb * 512 + col);
        for (int nIt = 0; nIt < cnt; ++nIt) {
            float4 w = w4p[(size_t)nIt * 128];
            const float4* sp = (const float4*)(ss + nIt * 64 + tr * 8);
            float4 s0 = sp[0], s1 = sp[1];
            float sarr[8] = {s0.x, s0.y, s0.z, s0.w, s1.x, s1.y, s1.z, s1.w};
#pragma unroll
            for (int i = 0; i < 8; ++i) {
                acc[i][0] = fmaf(sarr[i], w.x, acc[i][0]);
                acc[i][1] = fmaf(sarr[i], w.y, acc[i][1]);
                acc[i][2] = fmaf(sarr[i], w.z, acc[i][2]);
                acc[i][3] = fmaf(sarr[i], w.w, acc[i][3]);
            }
        }
    }
#pragma unroll
    for (int i = 0; i < 8; ++i) {
        int row = tr * 8 + i;
#pragma unroll
        for (int c = 0; c < 4; ++c)
            atomicAdd(&P[row * 512 + col + c], acc[i][c]);
    }
}

// ---------------- final: logits = relu(P+b4) @ W5 + b5; log_softmax rows ----------------
__global__ void k_final(const float* __restrict__ P, const float* __restrict__ b4,
                        const float* __restrict__ W5, const float* __restrict__ b5,
                        float* __restrict__ out) {
    __shared__ float p[HID];
    __shared__ float z[NCLS];
    __shared__ float red[256];
    int i = blockIdx.x;
    int tid = threadIdx.x;
    for (int k = tid; k < HID; k += 256) p[k] = fmaxf(P[i * HID + k] + b4[k], 0.f);
    __syncthreads();
    for (int c = tid; c < NCLS; c += 256) {
        float acc = b5[c];
        for (int k = 0; k < HID; ++k) acc = fmaf(p[k], W5[(size_t)k * NCLS + c], acc);
        z[c] = acc;
    }
    __syncthreads();
    float m = -INFINITY;
    for (int c = tid; c < NCLS; c += 256) m = fmaxf(m, z[c]);
    red[tid] = m;
    __syncthreads();
    for (int s = 128; s > 0; s >>= 1) {
        if (tid < s) red[tid] = fmaxf(red[tid], red[tid + s]);
        __syncthreads();
    }
    m = red[0];
    __syncthreads();
    float sum = 0.f;
    for (int c = tid; c < NCLS; c += 256) sum += expf(z[c] - m);
    red[tid] = sum;
    __syncthreads();
    for (int s = 128; s > 0; s >>= 1) {
        if (tid < s) red[tid] += red[tid + s];
        __syncthreads();
    }
    float lse = m + logf(red[0]);
    for (int c = tid; c < NCLS; c += 256) out[i * NCLS + c] = z[c] - lse;
}

extern "C" void kernel_launch(void* const* d_in, const int* in_sizes, int n_in,
                              void* d_out, int out_size, void* d_ws, size_t ws_size,
                              hipStream_t stream) {
    const int* adj = (const int*)d_in[0];
    const int* src = adj;
    const int* dst = adj + NE;
    const float* feat = (const float*)d_in[1];
    const float* W1 = (const float*)d_in[2];
    const float* b1 = (const float*)d_in[3];
    const float* W2 = (const float*)d_in[4];
    const float* b2 = (const float*)d_in[5];
    const float* W3 = (const float*)d_in[6];
    const float* b3 = (const float*)d_in[7];
    const float* Wlin = (const float*)d_in[8];
    const float* blin = (const float*)d_in[9];
    const float* W4 = (const float*)d_in[10];
    const float* b4 = (const float*)d_in[11];
    const float* W5 = (const float*)d_in[12];
    const float* b5 = (const float*)d_in[13];
    float* out = (float*)d_out;

    char* ws = (char*)d_ws;
    float* dinv = (float*)ws;                     ws += (size_t)NN * 4;
    int* cnt    = (int*)ws;                       ws += (size_t)NN * 4;
    int* off    = (int*)ws;                       ws += (size_t)NN * 4;
    int* cur    = (int*)ws;                       ws += (size_t)NN * 4;
    int* gtot   = (int*)ws;                       ws += 16;
    int* eidx   = (int*)ws;                       ws += (size_t)NE * 4;
    float* enorm= (float*)ws;                     ws += (size_t)NE * 4;
    float* bufA = (float*)ws;                     ws += (size_t)NN * 64 * 4;
    float* bufB = (float*)ws;                     ws += (size_t)NN * 64 * 4;
    float* P    = (float*)ws;                     ws += 64 * HID * 4;

    const int NB_N = (NN + 255) / 256;   // 391
    const int NB_E = NE / 256;           // 6250
    const int NB_G = NN / 32;            // 3125
    const int NB_GA = NN / 4;            // 25000 (4 nodes/block, wave per node)
    const int NB_T = 4 * TG_NCH;         // 1044

    // CSR + degree norm (built once, reused by all 3 conv layers)
    k_init<<<NB_N, 256, 0, stream>>>(cnt, gtot);
    k_count<<<NB_E, 256, 0, stream>>>(dst, cnt);
    k_off<<<NB_N, 256, 0, stream>>>(cnt, dinv, off, cur, gtot);
    k_fill<<<NB_E, 256, 0, stream>>>(src, dst, dinv, off, cur, eidx, enorm);

    // layer 1
    k_gemm64b<false, false><<<NB_G, 256, 0, stream>>>(feat, W1, nullptr, nullptr, bufA);
    k_gather<<<NB_GA, 256, 0, stream>>>(eidx, enorm, off, cnt, dinv, bufA, bufB);
    // layer 2
    k_gemm64b<true, false><<<NB_G, 256, 0, stream>>>(bufB, W2, b1, nullptr, bufA);
    k_gather<<<NB_GA, 256, 0, stream>>>(eidx, enorm, off, cnt, dinv, bufA, bufB);
    // layer 3
    k_gemm64b<true, false><<<NB_G, 256, 0, stream>>>(bufB, W3, b2, nullptr, bufA);
    k_gather<<<NB_GA, 256, 0, stream>>>(eidx, enorm, off, cnt, dinv, bufA, bufB);
    // scores = relu(bufB + b3) @ Wlin + blin
    k_gemm64b<true, true><<<NB_G, 256, 0, stream>>>(bufB, Wlin, b3, blin, bufA);

    // P = scores^T @ W4
    k_zero<<<(64 * HID + 255) / 256, 256, 0, stream>>>(P, 64 * HID);
    k_tgemm2<<<NB_T, 256, 0, stream>>>(bufA, W4, P);

    // logits + log_softmax
    k_final<<<64, 256, 0, stream>>>(P, b4, W5, b5, out);
}

// Round 3
// 958.905 us; speedup vs baseline: 2.1928x; 1.1197x over previous
//
#include <hip/hip_runtime.h>
#include <math.h>

#define NN 100000
#define NE 1600000
#define HID 512
#define NCLS 393

// ---------------- CSR build ----------------
__global__ void k_init(int* __restrict__ cnt, int* __restrict__ gtot) {
    int i = blockIdx.x * 256 + threadIdx.x;
    if (i < NN) cnt[i] = 0;
    if (i == 0) *gtot = 0;
}

__global__ void k_count(const int* __restrict__ dst, int* __restrict__ cnt) {
    int e = blockIdx.x * 256 + threadIdx.x;
    if (e < NE) atomicAdd(&cnt[dst[e]], 1);
}

// dinv = rsqrt(1+cnt); off = bump-alloc (disjoint contiguous ranges form a valid CSR); cur = 0
__global__ void k_off(const int* __restrict__ cnt, float* __restrict__ dinv,
                      int* __restrict__ off, int* __restrict__ cur, int* __restrict__ gtot) {
    int i = blockIdx.x * 256 + threadIdx.x;
    if (i < NN) {
        int c = cnt[i];
        dinv[i] = rsqrtf(1.0f + (float)c);
        off[i] = atomicAdd(gtot, c);
        cur[i] = 0;
    }
}

// pack (src, norm) into int2 so gather does one 8B load per edge
__global__ void k_fill(const int* __restrict__ src, const int* __restrict__ dst,
                       const float* __restrict__ dinv, const int* __restrict__ off,
                       int* __restrict__ cur, int2* __restrict__ epack) {
    int e = blockIdx.x * 256 + threadIdx.x;
    if (e < NE) {
        int s = src[e], d = dst[e];
        int pos = off[d] + atomicAdd(&cur[d], 1);
        epack[pos] = make_int2(s, __float_as_int(dinv[s] * dinv[d]));
    }
}

// ---------------- row GEMM: out = act(x) @ W (+bout) ----------------
template<bool IN_ACT, bool OUT_BIAS>
__global__ void k_gemm64b(const float* __restrict__ x, const float* __restrict__ W,
                          const float* __restrict__ bin, const float* __restrict__ bout,
                          float* __restrict__ out) {
    __shared__ float Ws[64 * 64];
    __shared__ float xs[32 * 64];
    int tid = threadIdx.x;
    size_t n0 = (size_t)blockIdx.x * 32;
    for (int i = tid; i < 1024; i += 256)
        ((float4*)Ws)[i] = ((const float4*)W)[i];
    for (int i = tid; i < 512; i += 256) {
        float4 v = ((const float4*)(x + n0 * 64))[i];
        if (IN_ACT) {
            int c = (i & 15) * 4;
            float4 bv = *(const float4*)(bin + c);
            v.x = fmaxf(v.x + bv.x, 0.f);
            v.y = fmaxf(v.y + bv.y, 0.f);
            v.z = fmaxf(v.z + bv.z, 0.f);
            v.w = fmaxf(v.w + bv.w, 0.f);
        }
        ((float4*)xs)[i] = v;
    }
    __syncthreads();
    int j = tid & 63, q = tid >> 6;
    float Wreg[64];
#pragma unroll
    for (int k = 0; k < 64; ++k) Wreg[k] = Ws[k * 64 + j];
    float bo = OUT_BIAS ? bout[j] : 0.f;
    for (int r = 0; r < 8; ++r) {
        int row = q * 8 + r;
        float acc = bo;
        const float4* xr = (const float4*)(xs + row * 64);
#pragma unroll
        for (int k4 = 0; k4 < 16; ++k4) {
            float4 xv = xr[k4];
            acc = fmaf(xv.x, Wreg[k4 * 4 + 0], acc);
            acc = fmaf(xv.y, Wreg[k4 * 4 + 1], acc);
            acc = fmaf(xv.z, Wreg[k4 * 4 + 2], acc);
            acc = fmaf(xv.w, Wreg[k4 * 4 + 3], acc);
        }
        out[(n0 + row) * 64 + j] = acc;
    }
}

// ---------------- CSR gather: one wave/node; 4 edges x 16 lanes x float4 ----------------
__global__ void k_gather2(const int2* __restrict__ epack, const int* __restrict__ off,
                          const int* __restrict__ cnt, const float* __restrict__ dinv,
                          const float* __restrict__ t, float* __restrict__ out) {
    int lane = threadIdx.x & 63;
    int n = (blockIdx.x * 256 + threadIdx.x) >> 6;
    if (n >= NN) return;
    int g = lane >> 4, f4 = lane & 15;
    int o = off[n], c = cnt[n];
    float ax = 0.f, ay = 0.f, az = 0.f, aw = 0.f;
    for (int b = 0; b < c; b += 4) {
        int idx = b + g;
        if (idx < c) {
            int2 ep = epack[o + idx];  // 16-lane broadcast
            float w = __int_as_float(ep.y);
            float4 v = *(const float4*)(t + (size_t)ep.x * 64 + f4 * 4);
            ax = fmaf(v.x, w, ax);
            ay = fmaf(v.y, w, ay);
            az = fmaf(v.z, w, az);
            aw = fmaf(v.w, w, aw);
        }
    }
    // reduce the 4 edge-groups
    ax += __shfl_xor(ax, 16); ay += __shfl_xor(ay, 16);
    az += __shfl_xor(az, 16); aw += __shfl_xor(aw, 16);
    ax += __shfl_xor(ax, 32); ay += __shfl_xor(ay, 32);
    az += __shfl_xor(az, 32); aw += __shfl_xor(aw, 32);
    if (lane < 16) {
        float dv = dinv[n];
        float d2 = dv * dv;
        float4 self = *(const float4*)(t + (size_t)n * 64 + f4 * 4);
        float4 r;
        r.x = ax + self.x * d2;
        r.y = ay + self.y * d2;
        r.z = az + self.z * d2;
        r.w = aw + self.w * d2;
        *(float4*)(out + (size_t)n * 64 + f4 * 4) = r;
    }
}

// ---------------- transpose GEMM, split-K, NO atomics ----------------
// grid = 4 colTiles * TG_SPLIT kchunks; partials to Pp[kc][64][512]
#define TG_SPLIT 192
#define TG_CHUNK 521  // ceil(100000/192); 192*521 = 100032
__global__ void k_tgemm3(const float* __restrict__ scores, const float* __restrict__ W4,
                         float* __restrict__ Pp) {
    __shared__ float ss[64 * 64];
    int colT = blockIdx.x & 3;
    int kc = blockIdx.x >> 2;
    int tid = threadIdx.x;
    int tc = tid & 31, tr = tid >> 5;  // tr in [0,8): rows tr*8..tr*8+7
    int col = colT * 128 + tc * 4;
    float acc[8][4];
#pragma unroll
    for (int i = 0; i < 8; ++i)
#pragma unroll
        for (int c = 0; c < 4; ++c) acc[i][c] = 0.f;
    int k0 = kc * TG_CHUNK;
    int k1 = min(k0 + TG_CHUNK, NN);
    for (int kb = k0; kb < k1; kb += 64) {
        int cnt = min(64, k1 - kb);
        __syncthreads();
        for (int i = tid; i < 1024; i += 256) {
            float4 v = {0.f, 0.f, 0.f, 0.f};
            if ((i >> 4) < cnt) v = ((const float4*)(scores + (size_t)kb * 64))[i];
            ((float4*)ss)[i] = v;
        }
        __syncthreads();
        const float* w4base = W4 + (size_t)kb * 512 + col;
        for (int nIt = 0; nIt < cnt; ++nIt) {
            float4 w = *(const float4*)(w4base + (size_t)nIt * 512);
            const float4* sp = (const float4*)(ss + nIt * 64 + tr * 8);
            float4 s0 = sp[0], s1 = sp[1];
            float sa[8] = {s0.x, s0.y, s0.z, s0.w, s1.x, s1.y, s1.z, s1.w};
#pragma unroll
            for (int i = 0; i < 8; ++i) {
                acc[i][0] = fmaf(sa[i], w.x, acc[i][0]);
                acc[i][1] = fmaf(sa[i], w.y, acc[i][1]);
                acc[i][2] = fmaf(sa[i], w.z, acc[i][2]);
                acc[i][3] = fmaf(sa[i], w.w, acc[i][3]);
            }
        }
    }
    float* pb = Pp + (size_t)kc * 64 * 512;
#pragma unroll
    for (int i = 0; i < 8; ++i) {
        int row = tr * 8 + i;
        *(float4*)(pb + row * 512 + col) = make_float4(acc[i][0], acc[i][1], acc[i][2], acc[i][3]);
    }
}

// ---------------- reduce partials: P[i] = sum_kc Pp[kc][i] ----------------
__global__ void k_reduce(const float* __restrict__ Pp, float* __restrict__ P) {
    int i = blockIdx.x * 256 + threadIdx.x;  // 32768 outputs
    float s0 = 0.f, s1 = 0.f, s2 = 0.f, s3 = 0.f;
    for (int kc = 0; kc < TG_SPLIT; kc += 4) {
        s0 += Pp[(size_t)(kc + 0) * 32768 + i];
        s1 += Pp[(size_t)(kc + 1) * 32768 + i];
        s2 += Pp[(size_t)(kc + 2) * 32768 + i];
        s3 += Pp[(size_t)(kc + 3) * 32768 + i];
    }
    P[i] = (s0 + s1) + (s2 + s3);
}

// ---------------- final: logits = relu(P+b4) @ W5 + b5; log_softmax rows ----------------
__global__ void k_final(const float* __restrict__ P, const float* __restrict__ b4,
                        const float* __restrict__ W5, const float* __restrict__ b5,
                        float* __restrict__ out) {
    __shared__ float p[HID];
    __shared__ float z[NCLS];
    __shared__ float red[256];
    int i = blockIdx.x;
    int tid = threadIdx.x;
    for (int k = tid; k < HID; k += 256) p[k] = fmaxf(P[i * HID + k] + b4[k], 0.f);
    __syncthreads();
    for (int c = tid; c < NCLS; c += 256) {
        float acc = b5[c];
        for (int k = 0; k < HID; ++k) acc = fmaf(p[k], W5[(size_t)k * NCLS + c], acc);
        z[c] = acc;
    }
    __syncthreads();
    float m = -INFINITY;
    for (int c = tid; c < NCLS; c += 256) m = fmaxf(m, z[c]);
    red[tid] = m;
    __syncthreads();
    for (int s = 128; s > 0; s >>= 1) {
        if (tid < s) red[tid] = fmaxf(red[tid], red[tid + s]);
        __syncthreads();
    }
    m = red[0];
    __syncthreads();
    float sum = 0.f;
    for (int c = tid; c < NCLS; c += 256) sum += expf(z[c] - m);
    red[tid] = sum;
    __syncthreads();
    for (int s = 128; s > 0; s >>= 1) {
        if (tid < s) red[tid] += red[tid + s];
        __syncthreads();
    }
    float lse = m + logf(red[0]);
    for (int c = tid; c < NCLS; c += 256) out[i * NCLS + c] = z[c] - lse;
}

extern "C" void kernel_launch(void* const* d_in, const int* in_sizes, int n_in,
                              void* d_out, int out_size, void* d_ws, size_t ws_size,
                              hipStream_t stream) {
    const int* adj = (const int*)d_in[0];
    const int* src = adj;
    const int* dst = adj + NE;
    const float* feat = (const float*)d_in[1];
    const float* W1 = (const float*)d_in[2];
    const float* b1 = (const float*)d_in[3];
    const float* W2 = (const float*)d_in[4];
    const float* b2 = (const float*)d_in[5];
    const float* W3 = (const float*)d_in[6];
    const float* b3 = (const float*)d_in[7];
    const float* Wlin = (const float*)d_in[8];
    const float* blin = (const float*)d_in[9];
    const float* W4 = (const float*)d_in[10];
    const float* b4 = (const float*)d_in[11];
    const float* W5 = (const float*)d_in[12];
    const float* b5 = (const float*)d_in[13];
    float* out = (float*)d_out;

    char* ws = (char*)d_ws;
    float* dinv  = (float*)ws;  ws += (size_t)NN * 4;
    int*   cnt   = (int*)ws;    ws += (size_t)NN * 4;
    int*   off   = (int*)ws;    ws += (size_t)NN * 4;
    int*   cur   = (int*)ws;    ws += (size_t)NN * 4;
    int*   gtot  = (int*)ws;    ws += 16;
    int2*  epack = (int2*)ws;   ws += (size_t)NE * 8;
    float* bufA  = (float*)ws;  ws += (size_t)NN * 64 * 4;
    float* bufB  = (float*)ws;  ws += (size_t)NN * 64 * 4;  // also Pp (192*32768 <= NN*64)
    float* P     = (float*)ws;  ws += 64 * HID * 4;

    const int NB_N = (NN + 255) / 256;
    const int NB_E = NE / 256;
    const int NB_G = NN / 32;
    const int NB_GA = NN / 4;
    const int NB_T = 4 * TG_SPLIT;  // 768

    // CSR + degree norm
    k_init<<<NB_N, 256, 0, stream>>>(cnt, gtot);
    k_count<<<NB_E, 256, 0, stream>>>(dst, cnt);
    k_off<<<NB_N, 256, 0, stream>>>(cnt, dinv, off, cur, gtot);
    k_fill<<<NB_E, 256, 0, stream>>>(src, dst, dinv, off, cur, epack);

    // layer 1
    k_gemm64b<false, false><<<NB_G, 256, 0, stream>>>(feat, W1, nullptr, nullptr, bufA);
    k_gather2<<<NB_GA, 256, 0, stream>>>(epack, off, cnt, dinv, bufA, bufB);
    // layer 2
    k_gemm64b<true, false><<<NB_G, 256, 0, stream>>>(bufB, W2, b1, nullptr, bufA);
    k_gather2<<<NB_GA, 256, 0, stream>>>(epack, off, cnt, dinv, bufA, bufB);
    // layer 3
    k_gemm64b<true, false><<<NB_G, 256, 0, stream>>>(bufB, W3, b2, nullptr, bufA);
    k_gather2<<<NB_GA, 256, 0, stream>>>(epack, off, cnt, dinv, bufA, bufB);
    // scores = relu(bufB + b3) @ Wlin + blin
    k_gemm64b<true, true><<<NB_G, 256, 0, stream>>>(bufB, Wlin, b3, blin, bufA);

    // P = scores^T @ W4 (split-K, plain stores; Pp aliases bufB which is now dead)
    float* Pp = bufB;
    k_tgemm3<<<NB_T, 256, 0, stream>>>(bufA, W4, Pp);
    k_reduce<<<(64 * HID) / 256, 256, 0, stream>>>(Pp, P);

    // logits + log_softmax
    k_final<<<64, 256, 0, stream>>>(P, b4, W5, b5, out);
}